// Round 4
// baseline (238.961 us; speedup 1.0000x reference)
//
#include <hip/hip_runtime.h>

#define CLS_LO 1.0e-4f
#define CLS_HI 0.9999f   // float(1.0 - 0.0001)

// ws layout (floats), per image b with stride S = 5*M + 3*64:
//   [0,M) counts | [M,4M) sums3 | [4M,5M) sumsq | [5M,5M+192) partials {cls,reg,np} x 64 slots
// After B*S floats: per-anchor mask, B*A uint8 (1 = anchor contributes neg-focal term).

__device__ __forceinline__ float smooth_l1(float d) {
    d = fabsf(d);
    return (d <= (1.0f / 9.0f)) ? (4.5f * d * d) : (d - (0.5f / 9.0f));
}

// ---------------- kernel A: per-anchor IoU assignment + rare positive work ----------------
__global__ void __launch_bounds__(256)
det_assign_kernel(const float* __restrict__ cls,
                  const float* __restrict__ reg,
                  const float* __restrict__ anc,
                  const float* __restrict__ ann,
                  float* __restrict__ ws,
                  unsigned char* __restrict__ mask,
                  int A, int C, int M)
{
    const int b   = blockIdx.y;
    const int tid = threadIdx.x;
    const int a   = blockIdx.x * 256 + tid;
    const int S   = 5 * M + 192;

    __shared__ float4 sbox[64];             // box corners [x1,y1,x2,y2]
    __shared__ float  slbl[64];
    __shared__ float  s_cnt[64], s_sx[64], s_sy[64], s_sz[64], s_sq[64];
    __shared__ float  s_part[4][3];

    if (tid < M) {
        const float* bp = ann + ((size_t)b * M + tid) * 5;
        sbox[tid] = make_float4(bp[0], bp[1], bp[2], bp[3]);
        slbl[tid] = bp[4];
        s_cnt[tid] = 0.f; s_sx[tid] = 0.f; s_sy[tid] = 0.f; s_sz[tid] = 0.f; s_sq[tid] = 0.f;
    }
    __syncthreads();

    float contrib_cls = 0.f, contrib_reg = 0.f, contrib_np = 0.f;

    if (a < A) {
        float4 av = ((const float4*)anc)[a];       // yx layout: [y1, x1, y2, x2]
        const float ay1 = av.x, ax1 = av.y, ay2 = av.z, ax2 = av.w;
        const float aw  = ax2 - ax1;
        const float ah  = ay2 - ay1;
        const float area_a = ah * aw;

        float best = -1.0f;
        int   bj   = 0;
#define IOU_BODY(j)                                                              \
        {                                                                        \
            const float4 bx = sbox[(j)];                                         \
            float iw = fminf(ax2, bx.z) - fmaxf(ax1, bx.x); iw = fmaxf(iw, 0.f); \
            float ih = fminf(ay2, bx.w) - fmaxf(ay1, bx.y); ih = fmaxf(ih, 0.f); \
            const float inter = iw * ih;                                         \
            const float ua = fmaxf(area_a + (bx.z - bx.x) * (bx.w - bx.y)        \
                                   - inter, 1e-8f);                              \
            const float iou = inter / ua;                                        \
            if (iou > best) { best = iou; bj = (j); }                            \
        }
        if (M == 32) {
            #pragma unroll
            for (int j = 0; j < 32; j++) IOU_BODY(j)
        } else {
            for (int j = 0; j < M; j++) IOU_BODY(j)
        }
#undef IOU_BODY
        const bool pos = best >= 0.5f;
        const bool neg = best < 0.4f;
        mask[(size_t)b * A + a] = (pos || neg) ? 1 : 0;

        if (pos) {
            contrib_np = 1.0f;

            // focal fixup at assigned class: focal kernel adds the uniform negative
            // term for every class; swap in the positive term at L.
            const float* cbase = cls + ((size_t)b * A + a) * (size_t)C;
            const int L = (int)slbl[bj];
            const float p = fminf(fmaxf(cbase[L], CLS_LO), CLS_HI);
            contrib_cls = 0.25f * (1.f - p) * (1.f - p) * (-__logf(p))
                        - 0.75f * p * p * (-__logf(1.f - p));

            const float* rp = reg + ((size_t)b * A + a) * 7;
            const float r0 = rp[0], r1 = rp[1], r2 = rp[2], r3 = rp[3];
            const float e0 = rp[4], e1 = rp[5], e2 = rp[6];

            const float4 bx = sbox[bj];
            float gw = bx.z - bx.x;
            float gh = bx.w - bx.y;
            const float gcx = bx.x + 0.5f * gw;
            const float gcy = bx.y + 0.5f * gh;
            gw = fmaxf(gw, 1.f);
            gh = fmaxf(gh, 1.f);
            const float acx = ax1 + 0.5f * aw;
            const float acy = ay1 + 0.5f * ah;
            contrib_reg = smooth_l1((gcy - acy) / ah - r0) +
                          smooth_l1((gcx - acx) / aw - r1) +
                          smooth_l1(logf(gh / ah) - r2) +
                          smooth_l1(logf(gw / aw) - r3);

            atomicAdd(&s_cnt[bj], 1.f);
            atomicAdd(&s_sx[bj], e0);
            atomicAdd(&s_sy[bj], e1);
            atomicAdd(&s_sz[bj], e2);
            atomicAdd(&s_sq[bj], e0 * e0 + e1 * e1 + e2 * e2);
        }
    }

    // reduce the three scalars: wave shuffle -> LDS -> one thread -> 64-way global slot
    for (int off = 32; off > 0; off >>= 1) {
        contrib_cls += __shfl_down(contrib_cls, off, 64);
        contrib_reg += __shfl_down(contrib_reg, off, 64);
        contrib_np  += __shfl_down(contrib_np,  off, 64);
    }
    if ((tid & 63) == 0) {
        s_part[tid >> 6][0] = contrib_cls;
        s_part[tid >> 6][1] = contrib_reg;
        s_part[tid >> 6][2] = contrib_np;
    }
    __syncthreads();

    float* wsb = ws + (size_t)b * S;
    if (tid < M) {
        const float c = s_cnt[tid];
        if (c != 0.f) {   // only blocks containing positive anchors fire global atomics
            atomicAdd(&wsb[tid], c);
            atomicAdd(&wsb[M + 3 * tid + 0], s_sx[tid]);
            atomicAdd(&wsb[M + 3 * tid + 1], s_sy[tid]);
            atomicAdd(&wsb[M + 3 * tid + 2], s_sz[tid]);
            atomicAdd(&wsb[4 * M + tid], s_sq[tid]);
        }
    }
    if (tid == 0) {
        const float c = s_part[0][0] + s_part[1][0] + s_part[2][0] + s_part[3][0];
        const float r = s_part[0][1] + s_part[1][1] + s_part[2][1] + s_part[3][1];
        const float n = s_part[0][2] + s_part[1][2] + s_part[2][2] + s_part[3][2];
        float* slot = wsb + 5 * M + 3 * (blockIdx.x & 63);
        if (c != 0.f) atomicAdd(&slot[0], c);
        if (r != 0.f) atomicAdd(&slot[1], r);
        if (n != 0.f) atomicAdd(&slot[2], n);
    }
}

// ---------------- kernel B: streaming masked focal reduction ----------------
// Tile = 64 anchors x (C/4) float4s. CPA4: compile-time float4s-per-anchor (20 for C=80),
// or 0 for the runtime-generic path.
template <int CPA4>
__global__ void __launch_bounds__(256)
det_focal_kernel(const float* __restrict__ cls,
                 const unsigned char* __restrict__ mask,
                 float* __restrict__ ws,
                 int A, int C, int M)
{
    const int b     = blockIdx.y;
    const int aBase = blockIdx.x * 64;
    const int tid   = threadIdx.x;
    const int S     = 5 * M + 192;
    const int cpa4  = CPA4 ? CPA4 : (C >> 2);

    __shared__ float smask[64];
    if (tid < 64) {
        const int a = aBase + tid;
        smask[tid] = (a < A) ? (float)mask[(size_t)b * A + a] : 0.f;
    }
    __syncthreads();

    const int nA = min(64, A - aBase);
    const float4* tile = (const float4*)(cls + ((size_t)b * A + aBase) * (size_t)C);
    float acc = 0.f;                          // sum of m * p^2 * log(1-p); scaled at end

#define FOCAL_BODY(IDX, MVAL)                                                     \
    {                                                                             \
        const float4 v = tile[(IDX)];                                             \
        float p, l, s = 0.f;                                                      \
        p = fminf(fmaxf(v.x, CLS_LO), CLS_HI); l = __logf(1.f - p); s = fmaf(p * p, l, s); \
        p = fminf(fmaxf(v.y, CLS_LO), CLS_HI); l = __logf(1.f - p); s = fmaf(p * p, l, s); \
        p = fminf(fmaxf(v.z, CLS_LO), CLS_HI); l = __logf(1.f - p); s = fmaf(p * p, l, s); \
        p = fminf(fmaxf(v.w, CLS_LO), CLS_HI); l = __logf(1.f - p); s = fmaf(p * p, l, s); \
        acc = fmaf((MVAL), s, acc);                                               \
    }

    if (CPA4 == 20 && nA == 64) {
        // full tile: 1280 float4s, 5 compile-time iterations, loads clustered
        #pragma unroll
        for (int k = 0; k < 5; k++) {
            const unsigned idx = (unsigned)tid + 256u * k;          // < 1280
            const float m = smask[(idx * 52429u) >> 20];            // idx/20, exact for idx < 262139
            FOCAL_BODY(idx, m)
        }
    } else {
        const int n4 = nA * cpa4;
        for (int idx = tid; idx < n4; idx += 256) {
            const float m = smask[(unsigned)idx / (unsigned)cpa4];
            FOCAL_BODY(idx, m)
        }
    }
#undef FOCAL_BODY

    for (int off = 32; off > 0; off >>= 1)
        acc += __shfl_down(acc, off, 64);
    __shared__ float sp[4];
    if ((tid & 63) == 0) sp[tid >> 6] = acc;
    __syncthreads();
    if (tid == 0) {
        const float tot = sp[0] + sp[1] + sp[2] + sp[3];
        // neg focal = 0.75 * p^2 * (-log(1-p))
        atomicAdd(&ws[(size_t)b * S + 5 * M + 3 * (blockIdx.x & 63) + 0], -0.75f * tot);
    }
}

// ---------------- final: combine partials, emit losses + embedding means ----------------
__global__ void __launch_bounds__(256)
det_final_kernel(const float* __restrict__ ws,
                 float* __restrict__ out,
                 int B, int M)
{
    const int t = threadIdx.x;
    const int S = 5 * M + 192;
    __shared__ float s_scal[8][3];
    __shared__ float s_emb[8];
    if (t < B) s_emb[t] = 0.f;

    // each 64-lane wave reduces one image's 64 partial slots
    const int k = t & 63;
    for (int b = t >> 6; b < B; b += 4) {
        const float* slot = ws + (size_t)b * S + 5 * M + 3 * k;
        float c = slot[0], r = slot[1], n = slot[2];
        for (int off = 32; off > 0; off >>= 1) {
            c += __shfl_down(c, off, 64);
            r += __shfl_down(r, off, 64);
            n += __shfl_down(n, off, 64);
        }
        if (k == 0) { s_scal[b][0] = c; s_scal[b][1] = r; s_scal[b][2] = n; }
    }
    __syncthreads();

    if (t < B * M) {
        const int b = t / M;
        const int m = t - b * M;
        const float* wsb = ws + (size_t)b * S;
        const float c = wsb[m];
        float mx = 0.f, my = 0.f, mz = 0.f, pa = 0.f;
        if (c > 0.f) {
            mx = wsb[M + 3 * m + 0] / c;
            my = wsb[M + 3 * m + 1] / c;
            mz = wsb[M + 3 * m + 2] / c;
            // sum |e - mean|^2 = sum|e|^2 - c*|mean|^2
            const float sq = wsb[4 * M + m] - c * (mx * mx + my * my + mz * mz);
            pa = sq / fmaxf(c * 3.f, 1.f);
        }
        out[3 + (size_t)(b * M + m) * 3 + 0] = mx;
        out[3 + (size_t)(b * M + m) * 3 + 1] = my;
        out[3 + (size_t)(b * M + m) * 3 + 2] = mz;
        atomicAdd(&s_emb[b], pa);
    }
    __syncthreads();

    if (t == 0) {
        float cl = 0.f, rl = 0.f, el = 0.f;
        for (int b = 0; b < B; b++) {
            const float np = s_scal[b][2];
            cl += s_scal[b][0] / fmaxf(np, 1.f);
            rl += s_scal[b][1] / fmaxf(4.f * np, 1.f);
            el += s_emb[b] / (float)M;
        }
        const float invB = 1.f / (float)B;
        out[0] = cl * invB;
        out[1] = rl * invB * 50.f;
        out[2] = el * invB;
    }
}

extern "C" void kernel_launch(void* const* d_in, const int* in_sizes, int n_in,
                              void* d_out, int out_size, void* d_ws, size_t ws_size,
                              hipStream_t stream) {
    const float* cls = (const float*)d_in[0];
    const float* reg = (const float*)d_in[1];
    const float* anc = (const float*)d_in[2];
    const float* ann = (const float*)d_in[3];
    float* out = (float*)d_out;
    float* ws  = (float*)d_ws;

    const int A = in_sizes[2] / 4;               // anchors: (1, A, 4)
    const int B = in_sizes[1] / (A * 7);         // regressions: (B, A, 7)
    const int C = in_sizes[0] / (B * A);         // classifications: (B, A, C)
    const int M = in_sizes[3] / (B * 5);         // annotations: (B, M, 5)
    const int S = 5 * M + 192;
    unsigned char* mask = (unsigned char*)d_ws + (size_t)B * S * sizeof(float);

    hipMemsetAsync(ws, 0, (size_t)B * S * sizeof(float), stream);

    dim3 gridA((A + 255) / 256, B);
    det_assign_kernel<<<gridA, 256, 0, stream>>>(cls, reg, anc, ann, ws, mask, A, C, M);

    dim3 gridB((A + 63) / 64, B);
    if (C == 80)
        det_focal_kernel<20><<<gridB, 256, 0, stream>>>(cls, mask, ws, A, C, M);
    else
        det_focal_kernel<0><<<gridB, 256, 0, stream>>>(cls, mask, ws, A, C, M);

    det_final_kernel<<<1, 256, 0, stream>>>(ws, out, B, M);
}